// Round 9
// baseline (158.335 us; speedup 1.0000x reference)
//
#include <hip/hip_runtime.h>
#include <hip/hip_bf16.h>

// z: (8,2048,64) f32 -> N=16384, D=64 ; codebook: (8192,64) f32
// outputs (f32, concat): z_q_st[1048576], vq_loss[1], idx[16384],
//   new_codebook[524288], new_cs[8192], new_ws[524288]
//
// Distance argmin via f16-split MFMA: x = xh + xl. dot(x,c) ~= Xh.Ch + Xh.Cl
// + Xl.Ch. argmin ||x-c||^2 == argmax (dot - 0.5||c||^2); -0.5||c||^2 is
// folded into the first MFMA's C operand.
//
// R9 = R8 resubmitted (R8's bench died on container infrastructure, not the
// kernel). NO LDS STAGING. R7's counter arithmetic: MFMA pipe floor 24.8 us,
// but the 4 waves/block all re-read the SAME B-frags from LDS (3072
// cyc/CU/group on the shared LDS port vs 3725 MFMA) and 2 barriers/group
// force lockstep phases -> MfmaUtil 41 + VALUBusy 44, both half-idle. Cxs is
// 2 MB = fully L2-resident in every XCD (guide common-mistake #7: don't
// LDS-stage data that cache-fits). k_prep writes Cxs in wave-read order (per
// 16-code tile: 4 frags x 64 lanes x 16 B) so each B-frag is ONE coalesced
// 1 KB global load. k_mfma: no LDS, no barriers, no DMA; each wave free-runs
// its 32 tiles (waves de-phase -> cross-pipe overlap) and covers 64 queries
// (4 q-tiles) so L2 traffic = 537 MB ~= 16-22 us < MFMA floor. Tail = R5's
// proven atomic-scatter k_assign + grid-stride k_ema.

#define NQ 16384
#define KC 8192
#define DD 64
#define NSPLIT 16
#define CSPLIT (KC / NSPLIT)   // 512 codes per wave job
#define NT (CSPLIT / 16)       // 32 tiles per split

typedef _Float16 half8 __attribute__((ext_vector_type(8)));
typedef _Float16 half4v __attribute__((ext_vector_type(4)));
typedef float f32x4 __attribute__((ext_vector_type(4)));
typedef unsigned int u32;

// ---------------- workspace layout (floats) ----------------
// [0)        nhcn    8192    (-0.5*||c||^2)
// [8192)     epart   32      (ema_cs partial sums, non-atomic)
// [8224)     parts   1024    (loss partials, one per k_assign block)
// [16384)    pmax    262144  (16 x 16384 partial max-u)
// [278528)   pidx    262144 u16 = 131072 f32
// [409600)   cnt     8192    (int, atomic counts)
// [417792)   dw      524288  (atomic scatter sums)
// [942080)   Cxs     524288  f32 = 1048576 halves (512 tiles x 2 KB)

// k_prep: f16-split codebook -> tile-fragment image in wave-read order +
// nhcn + ema partials + zeroing of dw/cnt.
// thread = (code c, j4); c = gid>>4, j4 = gid&15 covers f32x4 d=4*j4..
// Image: tile T = c>>4 owns 4 frags x 64 half8: frag fr in {Ch k[0:32),
// Ch k[32:64), Cl k[0:32), Cl k[32:64)}; slot = ((T*4+fr)*64 + q*16 + n)*8
// + ihalf*4 where n = c&15, q = (j4>>1)&3, ihalf = j4&1, fr = (j4>>3) or +2.
__global__ __launch_bounds__(256) void k_prep(
    const float* __restrict__ cb, const float* __restrict__ ema_cs,
    _Float16* __restrict__ Cxs, float* __restrict__ nhcn,
    float* __restrict__ epart, float* __restrict__ dw, int* __restrict__ cnt) {
  const int t = threadIdx.x;
  const int gid = blockIdx.x * 256 + t;
  const int c = gid >> 4;
  const int j4 = gid & 15;

  // zero atomic accumulators for this iteration
  ((f32x4*)dw)[gid] = f32x4{0.f, 0.f, 0.f, 0.f};
  if (gid < KC) cnt[gid] = 0;

  const f32x4 v = ((const f32x4*)cb)[gid];
  half4v hh, ll;
  float s = 0.f;
#pragma unroll
  for (int e = 0; e < 4; ++e) {
    const float f = v[e];
    const _Float16 h = (_Float16)f;
    hh[e] = h;
    ll[e] = (_Float16)(f - (float)h);
    s = fmaf(f, f, s);
  }
  const int tileA = c >> 4;
  const int n = c & 15;
  const int q = (j4 >> 1) & 3;
  const int ihalf = j4 & 1;
  const int frh = j4 >> 3;
  *(half4v*)(Cxs + ((size_t)((tileA * 4 + frh) * 64 + q * 16 + n)) * 8 +
             ihalf * 4) = hh;
  *(half4v*)(Cxs + ((size_t)((tileA * 4 + frh + 2) * 64 + q * 16 + n)) * 8 +
             ihalf * 4) = ll;

  // row sumsq: reduce across the 16 lanes of this row (lanes j4=0..15)
#pragma unroll
  for (int off = 1; off < 16; off <<= 1) s += __shfl_xor(s, off, 64);
  if (j4 == 0) nhcn[c] = -0.5f * s;

  // ema partials: blocks 0..31 each reduce 256 values (non-atomic write)
  if (blockIdx.x < 32) {
    float su = ema_cs[blockIdx.x * 256 + t];
#pragma unroll
    for (int off = 1; off < 64; off <<= 1) su += __shfl_xor(su, off, 64);
    __shared__ float ss[4];
    if ((t & 63) == 0) ss[t >> 6] = su;
    __syncthreads();
    if (t == 0) epart[blockIdx.x] = ss[0] + ss[1] + ss[2] + ss[3];
  }
}

// MFMA argmax, zero-LDS. 256-thread block = 4 waves x 64 queries (4 q-tiles
// each); wave job = 512 codes (split) = 32 tiles. Per tile: 4 coalesced 1 KB
// B-frag loads straight from L2-resident Cxs + nc gather, then 4 independent
// 6-deep MFMA chains (24 MFMA) + argmax. No barriers anywhere in the loop ->
// waves de-phase and the compiler pipelines loads under MFMA (unroll 4).
// launch_bounds (256,3): VGPR cap 170 >> expected ~120-150 (tight caps
// collapse the allocator -> 32 VGPR + GB-scale scratch, R3/R4).
__global__ __launch_bounds__(256, 3) void k_mfma(
    const float* __restrict__ z, const _Float16* __restrict__ Cxs,
    const float* __restrict__ nhcn, float* __restrict__ pmax,
    unsigned short* __restrict__ pidx) {
  const int t = threadIdx.x;
  const int lane = t & 63;
  const int w = t >> 6;
  const int split = blockIdx.y;
  const int Qw = blockIdx.x * 256 + w * 64;
  const int n16 = lane & 15;
  const int quad = lane >> 4;

  // A-frags: z rows -> f16 split in registers (layout: lane holds
  // A[m=lane&15][k=(lane>>4)*8+j]; frag hf covers k/d in [32*hf, 32*hf+32)).
  const f32x4* __restrict__ z4 = (const f32x4*)z;
  half8 aH0[4], aH1[4], aL0[4], aL1[4];
#pragma unroll
  for (int qt = 0; qt < 4; ++qt) {
    const size_t row16 = (size_t)(Qw + qt * 16 + n16) * 16;
#pragma unroll
    for (int hf = 0; hf < 2; ++hf) {
      const size_t rb = row16 + hf * 8 + quad * 2;
      const f32x4 va = z4[rb];
      const f32x4 vb = z4[rb + 1];
      half8 H, L;
#pragma unroll
      for (int e = 0; e < 4; ++e) {
        const float fa = va[e], fb = vb[e];
        const _Float16 ha = (_Float16)fa, hb = (_Float16)fb;
        H[e] = ha; H[e + 4] = hb;
        L[e] = (_Float16)(fa - (float)ha);
        L[e + 4] = (_Float16)(fb - (float)hb);
      }
      if (hf == 0) { aH0[qt] = H; aL0[qt] = L; }
      else         { aH1[qt] = H; aL1[qt] = L; }
    }
  }

  float best[4][4];
  int bidx[4][4];
#pragma unroll
  for (int qt = 0; qt < 4; ++qt)
#pragma unroll
    for (int r = 0; r < 4; ++r) {
      best[qt][r] = -3.4e38f;
      bidx[qt][r] = 0;
    }

  const half8* __restrict__ gx8 = (const half8*)Cxs;
  const int C0 = split * CSPLIT;
  const int Tbase = split * NT;

#pragma unroll 4
  for (int tt = 0; tt < NT; ++tt) {
    const int fb = (Tbase + tt) * 256 + lane;  // (T*4+0)*64 + lane
    const half8 b0 = gx8[fb];        // Ch k[0,32)
    const half8 b1 = gx8[fb + 64];   // Ch k[32,64)
    const half8 b2 = gx8[fb + 128];  // Cl k[0,32)
    const half8 b3 = gx8[fb + 192];  // Cl k[32,64)
    const int c = C0 + tt * 16 + n16;
    const float nc = nhcn[c];
    const f32x4 ncv = {nc, nc, nc, nc};
#pragma unroll
    for (int qt = 0; qt < 4; ++qt) {
      // first MFMA reads C=ncv, writes D=acc (no per-qt init movs)
      f32x4 acc =
          __builtin_amdgcn_mfma_f32_16x16x32_f16(aH0[qt], b0, ncv, 0, 0, 0);
      acc = __builtin_amdgcn_mfma_f32_16x16x32_f16(aH1[qt], b1, acc, 0, 0, 0);
      acc = __builtin_amdgcn_mfma_f32_16x16x32_f16(aH0[qt], b2, acc, 0, 0, 0);
      acc = __builtin_amdgcn_mfma_f32_16x16x32_f16(aH1[qt], b3, acc, 0, 0, 0);
      acc = __builtin_amdgcn_mfma_f32_16x16x32_f16(aL0[qt], b0, acc, 0, 0, 0);
      acc = __builtin_amdgcn_mfma_f32_16x16x32_f16(aL1[qt], b1, acc, 0, 0, 0);
#pragma unroll
      for (int r = 0; r < 4; ++r) {
        const float u = acc[r];
        if (u > best[qt][r]) { best[qt][r] = u; bidx[qt][r] = c; }
      }
    }
  }

#pragma unroll
  for (int qt = 0; qt < 4; ++qt)
#pragma unroll
    for (int r = 0; r < 4; ++r) {
      float u = best[qt][r];
      int c = bidx[qt][r];
#pragma unroll
      for (int off = 1; off < 16; off <<= 1) {
        const float u2 = __shfl_xor(u, off, 64);
        const int c2 = __shfl_xor(c, off, 64);
        if (u2 > u || (u2 == u && c2 < c)) { u = u2; c = c2; }
      }
      if (n16 == 0) {
        const int q = Qw + qt * 16 + quad * 4 + r;
        pmax[(size_t)split * NQ + q] = u;
        pidx[(size_t)split * NQ + q] = (unsigned short)c;
      }
    }
}

// q-partitioned: merge partial argmax (16 splits, non-redundant: lane l16
// owns split l16), gather z_q, write idx, scatter-add dw/cnt via global
// atomics, loss partial (non-atomic, one float per block). 16 queries/block.
__global__ __launch_bounds__(256) void k_assign(
    const float* __restrict__ z, const float* __restrict__ cb,
    const float* __restrict__ pmax, const unsigned short* __restrict__ pidx,
    float* __restrict__ out_zq, float* __restrict__ out_idx,
    float* __restrict__ dw, int* __restrict__ cnt,
    float* __restrict__ parts) {
  const int t = threadIdx.x;
  const int lane = t & 63;
  const int w = t >> 6;
  const int l16 = t & 15;        // split index, also dim-quad index
  const int q = blockIdx.x * 16 + (t >> 4);

  float v = pmax[(size_t)l16 * NQ + q];
  int i = (int)pidx[(size_t)l16 * NQ + q];
#pragma unroll
  for (int off = 1; off < 16; off <<= 1) {
    const float v2 = __shfl_xor(v, off, 64);
    const int i2 = __shfl_xor(i, off, 64);
    if (v2 > v || (v2 == v && i2 < i)) { v = v2; i = i2; }
  }
  const int k = i;  // all 16 lanes of the q-group agree

  const f32x4 zv = ((const f32x4*)z)[(size_t)q * 16 + l16];
  const f32x4 cv = ((const f32x4*)cb)[(size_t)k * 16 + l16];
  ((f32x4*)out_zq)[(size_t)q * 16 + l16] = cv;  // z + (z_q - z)

  float sq = 0.f;
#pragma unroll
  for (int e = 0; e < 4; ++e) {
    const float d = zv[e] - cv[e];
    sq = fmaf(d, d, sq);
  }
  // scatter: 4 f32 atomics per thread (coalesced 16B per thread)
#pragma unroll
  for (int e = 0; e < 4; ++e)
    atomicAdd(&dw[(size_t)k * DD + l16 * 4 + e], zv[e]);
  if (l16 == 0) {
    atomicAdd(&cnt[k], 1);
    out_idx[q] = (float)k;  // exact in f32 (k < 8192)
  }

  // loss partial: full-wave sum then block sum
#pragma unroll
  for (int off = 1; off < 64; off <<= 1) sq += __shfl_xor(sq, off, 64);
  __shared__ float ss[4];
  if (lane == 0) ss[w] = sq;
  __syncthreads();
  if (t == 0) parts[blockIdx.x] = ss[0] + ss[1] + ss[2] + ss[3];
}

// grid-stride EMA/normalize pass over K x D. One f32x4 per thread; 512
// blocks x 256 threads = exactly K*D/4. Block 0 reduces the loss partials.
__global__ __launch_bounds__(256) void k_ema(
    const float* __restrict__ ema_cs, const float* __restrict__ ema_ws,
    const float* __restrict__ dw, const int* __restrict__ cnt,
    const float* __restrict__ epart, const float* __restrict__ parts,
    float* __restrict__ out_ncs, float* __restrict__ out_ncb,
    float* __restrict__ out_nws, float* __restrict__ out_loss) {
  const int t = threadIdx.x;
  const int gid = blockIdx.x * 256 + t;
  const int k = gid >> 4;
  const int l16 = gid & 15;

  // n = 0.99*sum(ema_cs) + 0.01*NQ  (sum(counts) == NQ exactly)
  float esum = 0.f;
#pragma unroll
  for (int b = 0; b < 32; ++b) esum += epart[b];
  const float n = 0.99f * esum + 0.01f * 16384.0f;

  const float cs = 0.99f * ema_cs[k] + 0.01f * (float)cnt[k];
  const float smoothed = (cs + 1e-5f) / (n + (float)KC * 1e-5f) * n;

  const f32x4 dwv = ((const f32x4*)dw)[gid];
  const f32x4 ew = ((const f32x4*)ema_ws)[gid];
  f32x4 nws, ncb;
#pragma unroll
  for (int e = 0; e < 4; ++e) {
    nws[e] = 0.99f * ew[e] + 0.01f * dwv[e];
    ncb[e] = nws[e] / smoothed;
  }
  ((f32x4*)out_nws)[gid] = nws;
  ((f32x4*)out_ncb)[gid] = ncb;
  if (l16 == 0) out_ncs[k] = cs;

  if (blockIdx.x == 0) {
    float s = 0.f;
    for (int i = t; i < 1024; i += 256) s += parts[i];
#pragma unroll
    for (int off = 1; off < 64; off <<= 1) s += __shfl_xor(s, off, 64);
    __shared__ float ls[4];
    if ((t & 63) == 0) ls[t >> 6] = s;
    __syncthreads();
    if (t == 0)
      *out_loss = 1.25f * (ls[0] + ls[1] + ls[2] + ls[3]) *
                  (1.0f / 1048576.0f);
  }
}

extern "C" void kernel_launch(void* const* d_in, const int* in_sizes, int n_in,
                              void* d_out, int out_size, void* d_ws,
                              size_t ws_size, hipStream_t stream) {
  const float* z = (const float*)d_in[0];
  const float* cb = (const float*)d_in[1];
  const float* ema_cs = (const float*)d_in[2];
  const float* ema_ws = (const float*)d_in[3];

  float* out = (float*)d_out;
  float* zq_out = out;              // 1048576
  float* loss_out = out + 1048576;  // 1
  float* idx_out = out + 1048577;   // 16384
  float* ncb_out = out + 1064961;   // 524288
  float* ncs_out = out + 1589249;   // 8192
  float* nws_out = out + 1597441;   // 524288

  float* ws = (float*)d_ws;
  float* nhcn = ws;                                       // 8192
  float* epart = ws + 8192;                               // 32
  float* parts = ws + 8224;                               // 1024
  float* pmax = ws + 16384;                               // 262144
  unsigned short* pidx = (unsigned short*)(ws + 278528);  // 262144 u16
  int* cnt = (int*)(ws + 409600);                         // 8192 int
  float* dw = ws + 417792;                                // 524288
  _Float16* Cxs = (_Float16*)(ws + 942080);               // 1048576 halves

  k_prep<<<KC * 16 / 256, 256, 0, stream>>>(cb, ema_cs, Cxs, nhcn, epart, dw,
                                            cnt);
  k_mfma<<<dim3(NQ / 256, NSPLIT), 256, 0, stream>>>(z, Cxs, nhcn, pmax, pidx);
  k_assign<<<NQ / 16, 256, 0, stream>>>(z, cb, pmax, pidx, zq_out, idx_out, dw,
                                        cnt, parts);
  k_ema<<<KC * DD / 4 / 256, 256, 0, stream>>>(ema_cs, ema_ws, dw, cnt, epart,
                                               parts, ncs_out, ncb_out,
                                               nws_out, loss_out);
}

// Round 10
// 157.019 us; speedup vs baseline: 1.0084x; 1.0084x over previous
//
#include <hip/hip_runtime.h>
#include <hip/hip_bf16.h>

// z: (8,2048,64) f32 -> N=16384, D=64 ; codebook: (8192,64) f32
// outputs (f32, concat): z_q_st[1048576], vq_loss[1], idx[16384],
//   new_codebook[524288], new_cs[8192], new_ws[524288]
//
// Distance argmin via f16-split MFMA: x = xh + xl. dot(x,c) ~= Xh.Ch + Xh.Cl
// + Xl.Ch. argmin ||x-c||^2 == argmax (dot - 0.5||c||^2); -0.5||c||^2 via
// the first MFMA's C operand. Codebook preprocessed ONCE (k_prep) into a
// tile-fragment image in wave-read order (linear, conflict-free).
//
// R10: WAVE-PRIVATE LDS PIPELINE — the structure that dodges both measured
// failure modes. R7 (shared LDS, 52us): barriers force lockstep + 4 waves
// re-read the same frags on one LDS port. R9 (zero-LDS, 67us): prefetch
// from L2 into REGISTERS costs VGPRs -> depth 1 -> latency-bound at 23%
// occupancy. Here each wave owns a private 2x8KB double buffer filled by
// global_load_lds (prefetch costs ZERO VGPRs), counted vmcnt(8) retires
// only the previous group, and there are NO barriers anywhere -> waves
// de-phase; a group's DMA flight time (~1 iteration of 48 MFMA + ds_reads)
// covers L2 latency without TLP. 4 q-tiles/wave share each ds_read set
// (safe now: the R6 failure mode was barrier lockstep, absent here).
// nh: per-wave duplicate writes into one shared LDS copy (benign race,
// each wave reads its own writes -> no barrier). LDS 66KB -> 2 blocks/CU
// = 8 self-sufficient waves; low occupancy is BY DESIGN.

#define NQ 16384
#define KC 8192
#define DD 64
#define NSPLIT 16
#define CSPLIT (KC / NSPLIT)   // 512 codes per wave job
#define NT (CSPLIT / 16)       // 32 tiles per split
#define NGROUP 16              // groups of 2 tiles per wave job
#define THALF 2048             // halves per tile image (4 KB)
#define GHALF 4096             // halves per group image (8 KB)

typedef _Float16 half8 __attribute__((ext_vector_type(8)));
typedef _Float16 half4v __attribute__((ext_vector_type(4)));
typedef float f32x4 __attribute__((ext_vector_type(4)));
typedef unsigned int u32;

__device__ __forceinline__ void async_copy16(const _Float16* g, _Float16* l) {
  __builtin_amdgcn_global_load_lds(
      (const __attribute__((address_space(1))) u32*)(const void*)g,
      (__attribute__((address_space(3))) u32*)(void*)l, 16, 0, 0);
}

// ---------------- workspace layout (floats) ----------------
// [0)        nhcn    8192    (-0.5*||c||^2)
// [8192)     epart   32      (ema_cs partial sums, non-atomic)
// [8224)     parts   1024    (loss partials, one per k_assign block)
// [16384)    pmax    262144  (16 x 16384 partial max-u)
// [278528)   pidx    262144 u16 = 131072 f32
// [409600)   cnt     8192    (int, atomic counts)
// [417792)   dw      524288  (atomic scatter sums)
// [942080)   Cxs     524288  f32 = 1048576 halves (512 tiles x 2 KB)

// k_prep: f16-split codebook -> tile-fragment image in wave-read order +
// nhcn + ema partials + zeroing of dw/cnt. (Identical to R9 — layout
// verified by R9's passing run.)
__global__ __launch_bounds__(256) void k_prep(
    const float* __restrict__ cb, const float* __restrict__ ema_cs,
    _Float16* __restrict__ Cxs, float* __restrict__ nhcn,
    float* __restrict__ epart, float* __restrict__ dw, int* __restrict__ cnt) {
  const int t = threadIdx.x;
  const int gid = blockIdx.x * 256 + t;
  const int c = gid >> 4;
  const int j4 = gid & 15;

  // zero atomic accumulators for this iteration
  ((f32x4*)dw)[gid] = f32x4{0.f, 0.f, 0.f, 0.f};
  if (gid < KC) cnt[gid] = 0;

  const f32x4 v = ((const f32x4*)cb)[gid];
  half4v hh, ll;
  float s = 0.f;
#pragma unroll
  for (int e = 0; e < 4; ++e) {
    const float f = v[e];
    const _Float16 h = (_Float16)f;
    hh[e] = h;
    ll[e] = (_Float16)(f - (float)h);
    s = fmaf(f, f, s);
  }
  const int tileA = c >> 4;
  const int n = c & 15;
  const int q = (j4 >> 1) & 3;
  const int ihalf = j4 & 1;
  const int frh = j4 >> 3;
  *(half4v*)(Cxs + ((size_t)((tileA * 4 + frh) * 64 + q * 16 + n)) * 8 +
             ihalf * 4) = hh;
  *(half4v*)(Cxs + ((size_t)((tileA * 4 + frh + 2) * 64 + q * 16 + n)) * 8 +
             ihalf * 4) = ll;

  // row sumsq: reduce across the 16 lanes of this row (lanes j4=0..15)
#pragma unroll
  for (int off = 1; off < 16; off <<= 1) s += __shfl_xor(s, off, 64);
  if (j4 == 0) nhcn[c] = -0.5f * s;

  // ema partials: blocks 0..31 each reduce 256 values (non-atomic write)
  if (blockIdx.x < 32) {
    float su = ema_cs[blockIdx.x * 256 + t];
#pragma unroll
    for (int off = 1; off < 64; off <<= 1) su += __shfl_xor(su, off, 64);
    __shared__ float ss[4];
    if ((t & 63) == 0) ss[t >> 6] = su;
    __syncthreads();
    if (t == 0) epart[blockIdx.x] = ss[0] + ss[1] + ss[2] + ss[3];
  }
}

// MFMA argmax, wave-private pipeline. 256-thread block = 4 waves x 64
// queries (4 q-tiles each); wave job = 512 codes (split) = 16 groups of 2
// tiles. Each wave: private 2 x 8 KB LDS double buffer, global_load_lds
// DMA one group ahead, s_waitcnt vmcnt(8) (never 0 until the last group),
// NO barriers. Per group: 8 ds_read_b128 + 2 ds_read_b32 feed 48 MFMA in 8
// independent 6-chains. Only VMEM in the loop = the DMAs (clean counting).
__global__ __launch_bounds__(256, 2) void k_mfma(
    const float* __restrict__ z, const _Float16* __restrict__ Cxs,
    const float* __restrict__ nhcn, float* __restrict__ pmax,
    unsigned short* __restrict__ pidx) {
  __shared__ _Float16 Bs[4 * 2 * GHALF];  // 4 waves x 2 bufs x 8 KB = 64 KB
  __shared__ float nh[CSPLIT];            // 2 KB (duplicate-written, no bar)
  const int t = threadIdx.x;
  const int lane = t & 63;
  const int w = t >> 6;
  const int split = blockIdx.y;
  const int Qw = blockIdx.x * 256 + w * 64;
  const int n16 = lane & 15;
  const int quad = lane >> 4;
  const int C0 = split * CSPLIT;

  _Float16* const wbase = Bs + w * 2 * GHALF;

  // nh: every wave writes the full 512 values (identical data, benign
  // race); each wave's reads are covered by its own program-order writes.
#pragma unroll
  for (int j = 0; j < 8; ++j) nh[j * 64 + lane] = nhcn[C0 + j * 64 + lane];

  // A-frags: z rows -> f16 split in registers (layout: lane holds
  // A[m=lane&15][k=(lane>>4)*8+j]; frag hf covers k/d in [32*hf, 32*hf+32)).
  const f32x4* __restrict__ z4 = (const f32x4*)z;
  half8 aH0[4], aH1[4], aL0[4], aL1[4];
#pragma unroll
  for (int qt = 0; qt < 4; ++qt) {
    const size_t row16 = (size_t)(Qw + qt * 16 + n16) * 16;
#pragma unroll
    for (int hf = 0; hf < 2; ++hf) {
      const size_t rb = row16 + hf * 8 + quad * 2;
      const f32x4 va = z4[rb];
      const f32x4 vb = z4[rb + 1];
      half8 H, L;
#pragma unroll
      for (int e = 0; e < 4; ++e) {
        const float fa = va[e], fb = vb[e];
        const _Float16 ha = (_Float16)fa, hb = (_Float16)fb;
        H[e] = ha; H[e + 4] = hb;
        L[e] = (_Float16)(fa - (float)ha);
        L[e + 4] = (_Float16)(fb - (float)hb);
      }
      if (hf == 0) { aH0[qt] = H; aL0[qt] = L; }
      else         { aH1[qt] = H; aL1[qt] = L; }
    }
  }

  float best[4][4];
  int bidx[4][4];
#pragma unroll
  for (int qt = 0; qt < 4; ++qt)
#pragma unroll
    for (int r = 0; r < 4; ++r) {
      best[qt][r] = -3.4e38f;
      bidx[qt][r] = 0;
    }

  // drain all prologue VMEM so only our DMAs are counted by vmcnt
  asm volatile("s_waitcnt vmcnt(0)" ::: "memory");

  const _Float16* const gbase = Cxs + (size_t)split * (NT * THALF);

  // prologue: DMA group 0 into buffer 0 (8 x 1 KB, zero VGPR cost)
#pragma unroll
  for (int p = 0; p < 8; ++p) {
    const int off = (lane + 64 * p) * 8;
    async_copy16(gbase + off, wbase + off);
  }

#pragma unroll 4
  for (int g = 0; g < NGROUP; ++g) {
    if (g + 1 < NGROUP) {
      // issue next group's DMA into the other (wave-private) buffer; its
      // reads finished last iteration in this wave's own program order.
      const _Float16* gsrc = gbase + (size_t)(g + 1) * GHALF;
      _Float16* ldst = wbase + ((g + 1) & 1) * GHALF;
#pragma unroll
      for (int p = 0; p < 8; ++p) {
        const int off = (lane + 64 * p) * 8;
        async_copy16(gsrc + off, ldst + off);
      }
      // retire group g's 8 DMAs; leave the 8 just-issued in flight
      asm volatile("s_waitcnt vmcnt(8)" ::: "memory");
    } else {
      asm volatile("s_waitcnt vmcnt(0)" ::: "memory");
    }

    const half8* __restrict__ buf8 = (const half8*)(wbase + (g & 1) * GHALF);
#pragma unroll
    for (int tl = 0; tl < 2; ++tl) {
      const int tt = g * 2 + tl;
      const half8 b0 = buf8[tl * 256 + lane];        // Ch k[0,32)
      const half8 b1 = buf8[tl * 256 + 64 + lane];   // Ch k[32,64)
      const half8 b2 = buf8[tl * 256 + 128 + lane];  // Cl k[0,32)
      const half8 b3 = buf8[tl * 256 + 192 + lane];  // Cl k[32,64)
      const int c = C0 + tt * 16 + n16;
      const float nc = nh[tt * 16 + n16];  // 16-addr broadcast, conflict-free
      const f32x4 ncv = {nc, nc, nc, nc};
#pragma unroll
      for (int qt = 0; qt < 4; ++qt) {
        // first MFMA reads C=ncv, writes D=acc (no per-qt init movs)
        f32x4 acc =
            __builtin_amdgcn_mfma_f32_16x16x32_f16(aH0[qt], b0, ncv, 0, 0, 0);
        acc = __builtin_amdgcn_mfma_f32_16x16x32_f16(aH1[qt], b1, acc, 0, 0, 0);
        acc = __builtin_amdgcn_mfma_f32_16x16x32_f16(aH0[qt], b2, acc, 0, 0, 0);
        acc = __builtin_amdgcn_mfma_f32_16x16x32_f16(aH1[qt], b3, acc, 0, 0, 0);
        acc = __builtin_amdgcn_mfma_f32_16x16x32_f16(aL0[qt], b0, acc, 0, 0, 0);
        acc = __builtin_amdgcn_mfma_f32_16x16x32_f16(aL1[qt], b1, acc, 0, 0, 0);
#pragma unroll
        for (int r = 0; r < 4; ++r) {
          const float u = acc[r];
          if (u > best[qt][r]) { best[qt][r] = u; bidx[qt][r] = c; }
        }
      }
    }
  }

#pragma unroll
  for (int qt = 0; qt < 4; ++qt)
#pragma unroll
    for (int r = 0; r < 4; ++r) {
      float u = best[qt][r];
      int c = bidx[qt][r];
#pragma unroll
      for (int off = 1; off < 16; off <<= 1) {
        const float u2 = __shfl_xor(u, off, 64);
        const int c2 = __shfl_xor(c, off, 64);
        if (u2 > u || (u2 == u && c2 < c)) { u = u2; c = c2; }
      }
      if (n16 == 0) {
        const int q = Qw + qt * 16 + quad * 4 + r;
        pmax[(size_t)split * NQ + q] = u;
        pidx[(size_t)split * NQ + q] = (unsigned short)c;
      }
    }
}

// q-partitioned: merge partial argmax (16 splits, non-redundant: lane l16
// owns split l16), gather z_q, write idx, scatter-add dw/cnt via global
// atomics, loss partial (non-atomic, one float per block). 16 queries/block.
__global__ __launch_bounds__(256) void k_assign(
    const float* __restrict__ z, const float* __restrict__ cb,
    const float* __restrict__ pmax, const unsigned short* __restrict__ pidx,
    float* __restrict__ out_zq, float* __restrict__ out_idx,
    float* __restrict__ dw, int* __restrict__ cnt,
    float* __restrict__ parts) {
  const int t = threadIdx.x;
  const int lane = t & 63;
  const int w = t >> 6;
  const int l16 = t & 15;        // split index, also dim-quad index
  const int q = blockIdx.x * 16 + (t >> 4);

  float v = pmax[(size_t)l16 * NQ + q];
  int i = (int)pidx[(size_t)l16 * NQ + q];
#pragma unroll
  for (int off = 1; off < 16; off <<= 1) {
    const float v2 = __shfl_xor(v, off, 64);
    const int i2 = __shfl_xor(i, off, 64);
    if (v2 > v || (v2 == v && i2 < i)) { v = v2; i = i2; }
  }
  const int k = i;  // all 16 lanes of the q-group agree

  const f32x4 zv = ((const f32x4*)z)[(size_t)q * 16 + l16];
  const f32x4 cv = ((const f32x4*)cb)[(size_t)k * 16 + l16];
  ((f32x4*)out_zq)[(size_t)q * 16 + l16] = cv;  // z + (z_q - z)

  float sq = 0.f;
#pragma unroll
  for (int e = 0; e < 4; ++e) {
    const float d = zv[e] - cv[e];
    sq = fmaf(d, d, sq);
  }
  // scatter: 4 f32 atomics per thread (coalesced 16B per thread)
#pragma unroll
  for (int e = 0; e < 4; ++e)
    atomicAdd(&dw[(size_t)k * DD + l16 * 4 + e], zv[e]);
  if (l16 == 0) {
    atomicAdd(&cnt[k], 1);
    out_idx[q] = (float)k;  // exact in f32 (k < 8192)
  }

  // loss partial: full-wave sum then block sum
#pragma unroll
  for (int off = 1; off < 64; off <<= 1) sq += __shfl_xor(sq, off, 64);
  __shared__ float ss[4];
  if (lane == 0) ss[w] = sq;
  __syncthreads();
  if (t == 0) parts[blockIdx.x] = ss[0] + ss[1] + ss[2] + ss[3];
}

// grid-stride EMA/normalize pass over K x D. One f32x4 per thread; 512
// blocks x 256 threads = exactly K*D/4. Block 0 reduces the loss partials.
__global__ __launch_bounds__(256) void k_ema(
    const float* __restrict__ ema_cs, const float* __restrict__ ema_ws,
    const float* __restrict__ dw, const int* __restrict__ cnt,
    const float* __restrict__ epart, const float* __restrict__ parts,
    float* __restrict__ out_ncs, float* __restrict__ out_ncb,
    float* __restrict__ out_nws, float* __restrict__ out_loss) {
  const int t = threadIdx.x;
  const int gid = blockIdx.x * 256 + t;
  const int k = gid >> 4;
  const int l16 = gid & 15;

  // n = 0.99*sum(ema_cs) + 0.01*NQ  (sum(counts) == NQ exactly)
  float esum = 0.f;
#pragma unroll
  for (int b = 0; b < 32; ++b) esum += epart[b];
  const float n = 0.99f * esum + 0.01f * 16384.0f;

  const float cs = 0.99f * ema_cs[k] + 0.01f * (float)cnt[k];
  const float smoothed = (cs + 1e-5f) / (n + (float)KC * 1e-5f) * n;

  const f32x4 dwv = ((const f32x4*)dw)[gid];
  const f32x4 ew = ((const f32x4*)ema_ws)[gid];
  f32x4 nws, ncb;
#pragma unroll
  for (int e = 0; e < 4; ++e) {
    nws[e] = 0.99f * ew[e] + 0.01f * dwv[e];
    ncb[e] = nws[e] / smoothed;
  }
  ((f32x4*)out_nws)[gid] = nws;
  ((f32x4*)out_ncb)[gid] = ncb;
  if (l16 == 0) out_ncs[k] = cs;

  if (blockIdx.x == 0) {
    float s = 0.f;
    for (int i = t; i < 1024; i += 256) s += parts[i];
#pragma unroll
    for (int off = 1; off < 64; off <<= 1) s += __shfl_xor(s, off, 64);
    __shared__ float ls[4];
    if ((t & 63) == 0) ls[t >> 6] = s;
    __syncthreads();
    if (t == 0)
      *out_loss = 1.25f * (ls[0] + ls[1] + ls[2] + ls[3]) *
                  (1.0f / 1048576.0f);
  }
}

extern "C" void kernel_launch(void* const* d_in, const int* in_sizes, int n_in,
                              void* d_out, int out_size, void* d_ws,
                              size_t ws_size, hipStream_t stream) {
  const float* z = (const float*)d_in[0];
  const float* cb = (const float*)d_in[1];
  const float* ema_cs = (const float*)d_in[2];
  const float* ema_ws = (const float*)d_in[3];

  float* out = (float*)d_out;
  float* zq_out = out;              // 1048576
  float* loss_out = out + 1048576;  // 1
  float* idx_out = out + 1048577;   // 16384
  float* ncb_out = out + 1064961;   // 524288
  float* ncs_out = out + 1589249;   // 8192
  float* nws_out = out + 1597441;   // 524288

  float* ws = (float*)d_ws;
  float* nhcn = ws;                                       // 8192
  float* epart = ws + 8192;                               // 32
  float* parts = ws + 8224;                               // 1024
  float* pmax = ws + 16384;                               // 262144
  unsigned short* pidx = (unsigned short*)(ws + 278528);  // 262144 u16
  int* cnt = (int*)(ws + 409600);                         // 8192 int
  float* dw = ws + 417792;                                // 524288
  _Float16* Cxs = (_Float16*)(ws + 942080);               // 1048576 halves

  k_prep<<<KC * 16 / 256, 256, 0, stream>>>(cb, ema_cs, Cxs, nhcn, epart, dw,
                                            cnt);
  k_mfma<<<dim3(NQ / 256, NSPLIT), 256, 0, stream>>>(z, Cxs, nhcn, pmax, pidx);
  k_assign<<<NQ / 16, 256, 0, stream>>>(z, cb, pmax, pidx, zq_out, idx_out, dw,
                                        cnt, parts);
  k_ema<<<KC * DD / 4 / 256, 256, 0, stream>>>(ema_cs, ema_ws, dw, cnt, epart,
                                               parts, ncs_out, ncb_out,
                                               nws_out, loss_out);
}